// Round 1
// 205.764 us; speedup vs baseline: 2.1904x; 2.1904x over previous
//
#include <hip/hip_runtime.h>

#define BATCH 16
#define CH    64
#define TLEN  200
#define NP    30
#define HID   128
#define NSEQ  (BATCH * NP)   // 480
#define ROWF  200            // hx row: 128 h + 64 x + 8 pad (400 B = 25*16B -> 2-way max bank aliasing)

typedef _Float16 half8 __attribute__((ext_vector_type(8)));
typedef float    f32x4 __attribute__((ext_vector_type(4)));

__device__ __forceinline__ float sigm_fast(float x) {
    return __builtin_amdgcn_rcpf(1.0f + __expf(-x));
}
__device__ __forceinline__ float tanh_fast(float x) {
    float xc = fminf(15.0f, fmaxf(-15.0f, x));
    float e = __expf(2.0f * xc);
    return (e - 1.0f) * __builtin_amdgcn_rcpf(e + 1.0f);
}

#define MFMA16(A, B, C) __builtin_amdgcn_mfma_f32_16x16x32_f16((A), (B), (C), 0, 0, 0)

// ---------------------------------------------------------------------------
// One fused kernel. Block = 2 sequences (240 blocks ~ 1/CU), 8 waves.
// Per step: gates[2x512] = [h | x_t] (K=192) @ [W_hh | W_ih]^T via
// mfma_f32_16x16x32_f16, padded to M=16 (rows 2-15 stay zero).
//   - W frags persist in registers: wave w owns gate tiles {16w,128+16w,256+16w,384+16w}
//     so C layout (col=lane&15, row=(lane>>4)*4+reg) puts (i,f,g,o) for
//     hid=16w+lane, seq=reg in ONE lane -> in-register activation, c in VGPRs.
//   - hx double-buffered in LDS -> single __syncthreads per step.
//   - x_t gathered by lanes 32..47 of each wave, depth-2 register prefetch.
// ---------------------------------------------------------------------------
__global__ __launch_bounds__(512) void fused_lstm(
    const float* __restrict__ x, const float* __restrict__ W_ih,
    const float* __restrict__ W_hh, const float* __restrict__ b_ih,
    const float* __restrict__ b_hh, const float* __restrict__ W_fc,
    const float* __restrict__ b_fc, float* __restrict__ out)
{
    const int tid = threadIdx.x;
    const int w   = tid >> 6;    // wave 0..7
    const int l   = tid & 63;    // lane
    const int lr  = l & 15;      // row/col sub-index
    const int lq  = l >> 4;      // k-block 0..3

    const int n0 = blockIdx.x * 2;
    const int b0 = n0 / NP;
    const int p0 = n0 % NP;      // even -> both seqs share b0

    __shared__ __align__(16) _Float16 hx[2][16][ROWF];

    // ---- B fragments: W rows [gate][k], k in [0,128)=W_hh, [128,192)=W_ih.
    // frag(T,kt): lane l holds B[n=gate_tile(T)+l%16][k=32*kt+8*(l/16)+i], i=0..7
    half8 bf[4][6];
#pragma unroll
    for (int T = 0; T < 4; ++T) {
        const int g = 128 * T + 16 * w + lr;
#pragma unroll
        for (int kt = 0; kt < 6; ++kt) {
            const int k0 = 32 * kt + 8 * lq;
            const float* src = (kt < 4) ? (W_hh + (size_t)g * HID + k0)
                                        : (W_ih + (size_t)g * CH + (k0 - 128));
            float4 f0 = *(const float4*)src;
            float4 f1 = *(const float4*)(src + 4);
            bf[T][kt] = (half8){(_Float16)f0.x, (_Float16)f0.y, (_Float16)f0.z, (_Float16)f0.w,
                                (_Float16)f1.x, (_Float16)f1.y, (_Float16)f1.z, (_Float16)f1.w};
        }
    }

    // bias per output col (lane's col = lr); folded into the MFMA C-init
    float bi, bff, bg, bo;
    {
        const int gb = 16 * w + lr;
        bi  = b_ih[gb]       + b_hh[gb];
        bff = b_ih[gb + 128] + b_hh[gb + 128];
        bg  = b_ih[gb + 256] + b_hh[gb + 256];
        bo  = b_ih[gb + 384] + b_hh[gb + 384];
    }

    // x loaders: lanes 32..47 of each wave -> 128 threads, one (seq, channel) each
    const bool isload = (l >= 32 && l < 48);
    int ls = 0, lc = 0;
    const float* xptr = nullptr;
    float x0v = 0.f, xa = 0.f, xb = 0.f;
    if (isload) {
        const int idx = w * 16 + (l - 32);   // 0..127
        ls = idx >> 6;                        // seq 0/1
        lc = idx & 63;                        // channel
        xptr = x + ((size_t)(b0 * CH + lc) * TLEN) * NP + (p0 + ls);
        x0v = xptr[0];                        // issue early, overlaps W staging
    }

    // zero both hx buffers (rows 2-15 stay zero forever -> clean M=16 padding)
    for (int i = tid; i < 2 * 16 * ROWF / 2; i += 512) ((unsigned*)hx)[i] = 0u;
    __syncthreads();
    if (isload) {
        hx[0][ls][128 + lc] = (_Float16)x0v;
        xa = xptr[(size_t)1 * NP];            // x_1  (written at step 0)
        xb = xptr[(size_t)2 * NP];            // x_2  (written at step 1)
    }
    float cst = 0.f;   // c-state: lanes 0..31 hold c[seq=l>>4][hid=16w+(l&15)]
    __syncthreads();

    auto step = [&](int t, int cur, int nxt, float& xr) {
        // A frags: lane l reads hx[cur][l%16][32*kt + 8*(l/16) .. +8]  (b128, 2-way max)
        const _Float16* hrow = &hx[cur][lr][8 * lq];
        half8 a0 = *(const half8*)(hrow);
        half8 a1 = *(const half8*)(hrow + 32);
        half8 a2 = *(const half8*)(hrow + 64);
        half8 a3 = *(const half8*)(hrow + 96);
        half8 a4 = *(const half8*)(hrow + 128);
        half8 a5 = *(const half8*)(hrow + 160);
        f32x4 ai = {bi,  bi,  bi,  bi };
        f32x4 af = {bff, bff, bff, bff};
        f32x4 ag = {bg,  bg,  bg,  bg };
        f32x4 ao = {bo,  bo,  bo,  bo };
#define MM4(A, KT)                                                      \
        ai = MFMA16(A, bf[0][KT], ai); af = MFMA16(A, bf[1][KT], af);   \
        ag = MFMA16(A, bf[2][KT], ag); ao = MFMA16(A, bf[3][KT], ao);
        MM4(a0, 0) MM4(a1, 1) MM4(a2, 2) MM4(a3, 3) MM4(a4, 4) MM4(a5, 5)
#undef MM4
        // seq1 lives in reg[1] of lanes 0-15 -> spread to lanes 16-31 (halves trans ops)
        float gi1 = __shfl_up(ai[1], 16);
        float gf1 = __shfl_up(af[1], 16);
        float gg1 = __shfl_up(ag[1], 16);
        float go1 = __shfl_up(ao[1], 16);
        if (l < 32) {
            const bool lo = (l < 16);
            float gi = lo ? ai[0] : gi1;
            float gf = lo ? af[0] : gf1;
            float gg = lo ? ag[0] : gg1;
            float go = lo ? ao[0] : go1;
            cst = sigm_fast(gf) * cst + sigm_fast(gi) * tanh_fast(gg);
            float hv = sigm_fast(go) * tanh_fast(cst);
            hx[nxt][lq][16 * w + lr] = (_Float16)hv;          // h_{t+1}
        } else if (l < 48) {
            hx[nxt][ls][128 + lc] = (_Float16)xr;             // x_{t+1}
            int tn = t + 3; if (tn > TLEN - 1) tn = TLEN - 1; // clamped tail loads (unused)
            xr = xptr[(size_t)tn * NP];
        }
        __syncthreads();
    };

#pragma unroll 1
    for (int t = 0; t < TLEN; t += 2) {
        step(t,     0, 1, xa);
        step(t + 1, 1, 0, xb);
    }

    // FC epilogue: h_T sits in hx[0] rows 0,1 (TLEN even)
    if (tid < 2 * CH) {
        const int s = tid >> 6, ch = tid & 63;
        const float* wf = W_fc + (size_t)ch * HID;
        float acc = b_fc[ch];
#pragma unroll
        for (int j8 = 0; j8 < 16; ++j8) {
            half8 hv = *(const half8*)&hx[0][s][8 * j8];
            float4 w0 = *(const float4*)(wf + 8 * j8);
            float4 w1 = *(const float4*)(wf + 8 * j8 + 4);
            acc += w0.x * (float)hv[0] + w0.y * (float)hv[1]
                 + w0.z * (float)hv[2] + w0.w * (float)hv[3]
                 + w1.x * (float)hv[4] + w1.y * (float)hv[5]
                 + w1.z * (float)hv[6] + w1.w * (float)hv[7];
        }
        out[(size_t)(n0 + s) * CH + ch] = acc;
    }
}

extern "C" void kernel_launch(void* const* d_in, const int* in_sizes, int n_in,
                              void* d_out, int out_size, void* d_ws, size_t ws_size,
                              hipStream_t stream) {
    (void)in_sizes; (void)n_in; (void)out_size; (void)d_ws; (void)ws_size;
    fused_lstm<<<NSEQ / 2, 512, 0, stream>>>(
        (const float*)d_in[0], (const float*)d_in[1], (const float*)d_in[2],
        (const float*)d_in[3], (const float*)d_in[4], (const float*)d_in[5],
        (const float*)d_in[6], (float*)d_out);
}